// Round 1
// baseline (8517.845 us; speedup 1.0000x reference)
//
#include <hip/hip_runtime.h>
#include <cstdint>

// Problem: B=32, S=1024, D=1024 ContractiveSequenceMixer
//   gates = sigmoid(x @ Wg^T + bg); pin = x @ Wi^T + bi   (precomputable)
//   scan t: mix = h @ Ws^T + bs + pin_t ; h = g_t*mix + (1-g_t)*h ; emit h
// out = [emitted (B,S,D) fp32 | final_state (B,D) fp32]
//
// Strategy:
//  K1-K3: prep (split x->bf16 hi/lo, build Wcat=[Wg;Wi] hi/lo, init h/flags)
//  K4: fused MFMA GEMM (split-bf16 3-term, K=1024,N=2048) -> G(ws), P(d_out)
//  K5: persistent 32-WG recurrence, flag-synced, Ws slice in VGPRs,
//      split-bf16 3-term matvec per step, h double-buffered in ws.
// ws usage ~265 MB.

#define BATCH 32
#define SEQ   1024
#define DIM   1024
static const size_t BSD = (size_t)BATCH * SEQ * DIM; // 33554432

typedef short  s16x8 __attribute__((ext_vector_type(8)));
typedef unsigned short u16x4 __attribute__((ext_vector_type(4)));
typedef float  f32x4 __attribute__((ext_vector_type(4)));

__device__ __forceinline__ unsigned short f2bf(float f) {
  union { float f; unsigned int u; } v; v.f = f;
  unsigned int r = v.u + 0x7fffu + ((v.u >> 16) & 1u);  // RNE
  return (unsigned short)(r >> 16);
}
__device__ __forceinline__ float bf2f(unsigned short h) {
  union { unsigned int u; float f; } v; v.u = ((unsigned int)h) << 16; return v.f;
}

__device__ __forceinline__ void gload_lds16(const void* g, void* l) {
  __builtin_amdgcn_global_load_lds(
      (const __attribute__((address_space(1))) void*)g,
      (__attribute__((address_space(3))) void*)l, 16, 0, 0);
}

// ---------------- prep kernels ----------------
__global__ void split_x_kernel(const float* __restrict__ x,
                               unsigned short* __restrict__ xh,
                               unsigned short* __restrict__ xl, long n4) {
  long i = (long)blockIdx.x * blockDim.x + threadIdx.x;
  const long stride = (long)gridDim.x * blockDim.x;
  for (; i < n4; i += stride) {
    f32x4 v = *(const f32x4*)&x[i * 4];
    u16x4 vh, vl;
#pragma unroll
    for (int j = 0; j < 4; ++j) {
      unsigned short hb = f2bf(v[j]);
      vh[j] = hb; vl[j] = f2bf(v[j] - bf2f(hb));
    }
    *(u16x4*)&xh[i * 4] = vh;
    *(u16x4*)&xl[i * 4] = vl;
  }
}

__global__ void split_w_kernel(const float* __restrict__ Wg,
                               const float* __restrict__ Wi,
                               unsigned short* __restrict__ wh,
                               unsigned short* __restrict__ wl) {
  long i = (long)blockIdx.x * blockDim.x + threadIdx.x; // 524288 float4 groups
  if (i >= (long)(2048 * 1024 / 4)) return;
  long flat = i * 4;
  int row = (int)(flat >> 10);
  int col = (int)(flat & 1023);
  const float* src = (row < 1024) ? &Wg[(size_t)row * 1024 + col]
                                  : &Wi[(size_t)(row - 1024) * 1024 + col];
  f32x4 v = *(const f32x4*)src;
  u16x4 vh, vl;
#pragma unroll
  for (int j = 0; j < 4; ++j) {
    unsigned short hb = f2bf(v[j]);
    vh[j] = hb; vl[j] = f2bf(v[j] - bf2f(hb));
  }
  *(u16x4*)&wh[flat] = vh;
  *(u16x4*)&wl[flat] = vl;
}

__global__ void init_kernel(unsigned int* h_hi, unsigned int* h_lo, int* flags) {
  int i = blockIdx.x * blockDim.x + threadIdx.x;  // 16384 needed
  if (i < 16384) { h_hi[i] = 0u; h_lo[i] = 0u; }
  if (i < 512) flags[i] = 0;
}

// ---------------- fused G/P GEMM (split-bf16, 3-term) ----------------
// out[r][c] = sum_k x[r][k]*Wcat[c][k], r<32768, c<2048, K=1024
// c<1024 -> G = sigmoid(out+bg) ; c>=1024 -> P = out+bi  (P lives in d_out)
__global__ __launch_bounds__(256) void gemm_gp_kernel(
    const unsigned short* __restrict__ xh, const unsigned short* __restrict__ xl,
    const unsigned short* __restrict__ wh, const unsigned short* __restrict__ wl,
    const float* __restrict__ bg, const float* __restrict__ bi,
    float* __restrict__ G, float* __restrict__ P) {
  __shared__ unsigned short sAh[128 * 32], sAl[128 * 32], sBh[128 * 32], sBl[128 * 32];
  const int tid = threadIdx.x;
  const int w = tid >> 6, l = tid & 63;
  const int wr = w >> 1, wc = w & 1;
  const int lr = l & 15, lk8 = (l >> 4) * 8;
  const size_t rBase = (size_t)blockIdx.x * 128;
  const int cBase = blockIdx.y * 128;

  f32x4 acc[4][4];
  f32x4 z = {0.f, 0.f, 0.f, 0.f};
#pragma unroll
  for (int m = 0; m < 4; ++m)
#pragma unroll
    for (int n = 0; n < 4; ++n) acc[m][n] = z;

  for (int kb = 0; kb < 32; ++kb) {
    const int k0 = kb * 32;
#pragma unroll
    for (int i = 0; i < 2; ++i) {
      const int chunk = w * 128 + i * 64 + l;
      const int row = chunk >> 2;
      const int c8 = (chunk & 3) * 8;
      gload_lds16(xh + (rBase + row) * 1024 + k0 + c8, &sAh[chunk * 8]);
      gload_lds16(xl + (rBase + row) * 1024 + k0 + c8, &sAl[chunk * 8]);
      gload_lds16(wh + (size_t)(cBase + row) * 1024 + k0 + c8, &sBh[chunk * 8]);
      gload_lds16(wl + (size_t)(cBase + row) * 1024 + k0 + c8, &sBl[chunk * 8]);
    }
    __syncthreads();

    s16x8 ah[4], al[4], bh[4], bl[4];
#pragma unroll
    for (int m = 0; m < 4; ++m) {
      ah[m] = *(const s16x8*)&sAh[(wr * 64 + m * 16 + lr) * 32 + lk8];
      al[m] = *(const s16x8*)&sAl[(wr * 64 + m * 16 + lr) * 32 + lk8];
    }
#pragma unroll
    for (int n = 0; n < 4; ++n) {
      bh[n] = *(const s16x8*)&sBh[(wc * 64 + n * 16 + lr) * 32 + lk8];
      bl[n] = *(const s16x8*)&sBl[(wc * 64 + n * 16 + lr) * 32 + lk8];
    }
#pragma unroll
    for (int m = 0; m < 4; ++m)
#pragma unroll
      for (int n = 0; n < 4; ++n)
        acc[m][n] = __builtin_amdgcn_mfma_f32_16x16x32_bf16(ah[m], bh[n], acc[m][n], 0, 0, 0);
#pragma unroll
    for (int m = 0; m < 4; ++m)
#pragma unroll
      for (int n = 0; n < 4; ++n)
        acc[m][n] = __builtin_amdgcn_mfma_f32_16x16x32_bf16(al[m], bh[n], acc[m][n], 0, 0, 0);
#pragma unroll
    for (int m = 0; m < 4; ++m)
#pragma unroll
      for (int n = 0; n < 4; ++n)
        acc[m][n] = __builtin_amdgcn_mfma_f32_16x16x32_bf16(ah[m], bl[n], acc[m][n], 0, 0, 0);
    __syncthreads();
  }

  const bool isG = (cBase < 1024);
#pragma unroll
  for (int m = 0; m < 4; ++m) {
#pragma unroll
    for (int n = 0; n < 4; ++n) {
      const int col = cBase + wc * 64 + n * 16 + lr;
      const size_t row0 = rBase + wr * 64 + m * 16 + (l >> 4) * 4;
#pragma unroll
      for (int i = 0; i < 4; ++i) {
        float v = acc[m][n][i];
        if (isG) {
          v += bg[col];
          v = 1.f / (1.f + expf(-v));
          G[(row0 + i) * 1024 + col] = v;
        } else {
          v += bi[col - 1024];
          P[(row0 + i) * 1024 + (col - 1024)] = v;
        }
      }
    }
  }
}

// ---------------- persistent recurrence kernel ----------------
// 32 WGs x 256 threads. WG w owns e-rows [w*32, w*32+32) for all 32 batches.
// Wave kq (0..3) handles K-quarter [kq*256, +256), out 32x32 via 2x2 16x16 frags.
// Ws slice (hi+lo) lives in VGPRs; h double-buffered (hi/lo bf16) in ws;
// flag[w]=t means h_t slice w is published (agent-scope release/acquire).
__global__ __launch_bounds__(256, 1) void recur_kernel(
    const float* __restrict__ Ws, const float* __restrict__ bs,
    const float* __restrict__ G, float* out,
    unsigned short* h_hi, unsigned short* h_lo, int* flags) {
  __shared__ float part[4][1024];
  const int w = blockIdx.x;   // e-slice
  const int e0 = w * 32;
  const int tid = threadIdx.x;
  const int kq = tid >> 6;    // wave id = K quarter
  const int l = tid & 63;
  const int lr = l & 15;
  const int lh4 = l >> 4;

  // Ws fragments -> registers (constant over time)
  s16x8 bhi[2][8], blo[2][8];
#pragma unroll
  for (int nt = 0; nt < 2; ++nt) {
#pragma unroll
    for (int c = 0; c < 8; ++c) {
      const int e = e0 + nt * 16 + lr;
      const int k = kq * 256 + c * 32 + lh4 * 8;
      const float* src = Ws + (size_t)e * DIM + k;
      f32x4 v0 = *(const f32x4*)src;
      f32x4 v1 = *(const f32x4*)(src + 4);
      s16x8 vh, vl;
#pragma unroll
      for (int j = 0; j < 4; ++j) {
        unsigned short hb = f2bf(v0[j]);
        vh[j] = (short)hb;
        vl[j] = (short)f2bf(v0[j] - bf2f(hb));
        unsigned short hb2 = f2bf(v1[j]);
        vh[4 + j] = (short)hb2;
        vl[4 + j] = (short)f2bf(v1[j] - bf2f(hb2));
      }
      bhi[nt][c] = vh; blo[nt][c] = vl;
    }
  }

  // epilogue mapping: thread handles outputs [ob][e0+oe .. +4)
  const int ob = (tid * 4) >> 5;
  const int oe = (tid * 4) & 31;
  const f32x4 bs4 = *(const f32x4*)&bs[e0 + oe];
  float hold[4] = {0.f, 0.f, 0.f, 0.f};

#pragma unroll 1
  for (int t = 0; t < SEQ; ++t) {
    // prefetch g,p (flag-independent; in flight during poll)
    const size_t gp_idx = ((size_t)ob * SEQ + t) * DIM + e0 + oe;
    f32x4 g4 = *(const f32x4*)&G[gp_idx];
    f32x4 p4 = *(const f32x4*)&out[gp_idx];

    // wait until all 32 slices of h_t are published
    {
      const int fi = l & 31;
      while (__hip_atomic_load(&flags[fi << 4], __ATOMIC_RELAXED,
                               __HIP_MEMORY_SCOPE_AGENT) < t) {
        __builtin_amdgcn_s_sleep(1);
      }
      __builtin_amdgcn_fence(__ATOMIC_ACQUIRE, "agent");
    }

    const unsigned short* Hh = h_hi + (size_t)(t & 1) * (BATCH * DIM);
    const unsigned short* Hl = h_lo + (size_t)(t & 1) * (BATCH * DIM);

    s16x8 ah[2][8], al[2][8];
#pragma unroll
    for (int c = 0; c < 8; ++c) {
#pragma unroll
      for (int mt = 0; mt < 2; ++mt) {
        const int bb = mt * 16 + lr;
        const int k = kq * 256 + c * 32 + lh4 * 8;
        ah[mt][c] = *(const s16x8*)&Hh[(size_t)bb * DIM + k];
        al[mt][c] = *(const s16x8*)&Hl[(size_t)bb * DIM + k];
      }
    }

    f32x4 z = {0.f, 0.f, 0.f, 0.f};
    f32x4 aA[2][2], aB[2][2], aC[2][2];
#pragma unroll
    for (int mt = 0; mt < 2; ++mt)
#pragma unroll
      for (int nt = 0; nt < 2; ++nt) { aA[mt][nt] = z; aB[mt][nt] = z; aC[mt][nt] = z; }

#pragma unroll
    for (int c = 0; c < 8; ++c) {
#pragma unroll
      for (int mt = 0; mt < 2; ++mt)
#pragma unroll
        for (int nt = 0; nt < 2; ++nt) {
          aA[mt][nt] = __builtin_amdgcn_mfma_f32_16x16x32_bf16(ah[mt][c], bhi[nt][c], aA[mt][nt], 0, 0, 0);
          aB[mt][nt] = __builtin_amdgcn_mfma_f32_16x16x32_bf16(al[mt][c], bhi[nt][c], aB[mt][nt], 0, 0, 0);
          aC[mt][nt] = __builtin_amdgcn_mfma_f32_16x16x32_bf16(ah[mt][c], blo[nt][c], aC[mt][nt], 0, 0, 0);
        }
    }

    // partial sums to LDS (C/D frag: row=4*(l>>4)+i, col=l&15)
#pragma unroll
    for (int mt = 0; mt < 2; ++mt)
#pragma unroll
      for (int nt = 0; nt < 2; ++nt) {
        f32x4 v = aA[mt][nt] + aB[mt][nt] + aC[mt][nt];
#pragma unroll
        for (int i = 0; i < 4; ++i)
          part[kq][(mt * 16 + lh4 * 4 + i) * 32 + nt * 16 + lr] = v[i];
      }
    __syncthreads();

    f32x4 r = *(const f32x4*)&part[0][tid * 4];
    r = r + *(const f32x4*)&part[1][tid * 4];
    r = r + *(const f32x4*)&part[2][tid * 4];
    r = r + *(const f32x4*)&part[3][tid * 4];

    f32x4 hn;
#pragma unroll
    for (int j = 0; j < 4; ++j) {
      const float mix = r[j] + bs4[j] + p4[j];
      const float g = g4[j];
      const float v = g * mix + (1.f - g) * hold[j];
      hold[j] = v; hn[j] = v;
    }
    *(f32x4*)&out[gp_idx] = hn;  // emitted (overwrites consumed P slot)

    u16x4 vh, vl;
#pragma unroll
    for (int j = 0; j < 4; ++j) {
      unsigned short hb = f2bf(hn[j]);
      vh[j] = hb; vl[j] = f2bf(hn[j] - bf2f(hb));
    }
    const size_t hb_idx = (size_t)((t + 1) & 1) * (BATCH * DIM) + (size_t)ob * DIM + e0 + oe;
    *(u16x4*)&h_hi[hb_idx] = vh;
    *(u16x4*)&h_lo[hb_idx] = vl;

    if (t == SEQ - 1)
      *(f32x4*)&out[BSD + (size_t)ob * DIM + e0 + oe] = hn;

    __syncthreads();
    if (tid == 0) {
      __builtin_amdgcn_fence(__ATOMIC_RELEASE, "agent");
      __hip_atomic_store(&flags[w << 4], t + 1, __ATOMIC_RELAXED, __HIP_MEMORY_SCOPE_AGENT);
    }
  }
}

// ---------------- launch ----------------
extern "C" void kernel_launch(void* const* d_in, const int* in_sizes, int n_in,
                              void* d_out, int out_size, void* d_ws, size_t ws_size,
                              hipStream_t stream) {
  (void)in_sizes; (void)n_in; (void)out_size; (void)ws_size;
  const float* x  = (const float*)d_in[0];
  const float* Wg = (const float*)d_in[1];
  const float* bg = (const float*)d_in[2];
  const float* Ws = (const float*)d_in[3];
  const float* bs = (const float*)d_in[4];
  const float* Wi = (const float*)d_in[5];
  const float* bi = (const float*)d_in[6];
  float* out = (float*)d_out;
  char* ws = (char*)d_ws;

  // ws layout (bytes): needs ~265 MB
  unsigned short* xh   = (unsigned short*)(ws);              // 64 MB
  unsigned short* xl   = (unsigned short*)(ws + 67108864);   // 64 MB
  unsigned short* wh   = (unsigned short*)(ws + 134217728);  // 4 MB
  unsigned short* wl   = (unsigned short*)(ws + 138412032);  // 4 MB
  float*          G    = (float*)(ws + 142606336);           // 128 MB
  unsigned short* h_hi = (unsigned short*)(ws + 276824064);  // 128 KB (2 bufs)
  unsigned short* h_lo = (unsigned short*)(ws + 276955136);  // 128 KB
  int*            flags= (int*)(ws + 277086208);             // 2 KB

  hipLaunchKernelGGL(split_x_kernel, dim3(4096), dim3(256), 0, stream,
                     x, xh, xl, (long)(BSD / 4));
  hipLaunchKernelGGL(split_w_kernel, dim3(2048), dim3(256), 0, stream, Wg, Wi, wh, wl);
  hipLaunchKernelGGL(init_kernel, dim3(64), dim3(256), 0, stream,
                     (unsigned int*)h_hi, (unsigned int*)h_lo, flags);
  hipLaunchKernelGGL(gemm_gp_kernel, dim3(256, 16), dim3(256), 0, stream,
                     xh, xl, wh, wl, bg, bi, G, out);
  hipLaunchKernelGGL(recur_kernel, dim3(32), dim3(256), 0, stream,
                     Ws, bs, G, out, h_hi, h_lo, flags);
}